// Round 6
// baseline (399.452 us; speedup 1.0000x reference)
//
#include <hip/hip_runtime.h>
#include <math.h>

#define C_DIM 256
#define NH 8
#define HD 32
#define BATCH 2
#define NPIX 2304        // 48*48
#define TK 64
#define NGRP (NPIX / 16) // 144 n-groups of 16
#define TPB 36           // K-tiles per attn block (full range, no split-K)
#define NBLK 576

typedef __attribute__((ext_vector_type(8))) short bf16x8;
typedef __attribute__((ext_vector_type(4))) float f32x4;

// workspace offsets (in shorts)
#define OFF_XT  0u
#define OFF_Q   1179648u
#define OFF_K   2359296u
#define OFF_V   3538944u
#define OFF_OT  4718592u
#define OFF_WQ  5898240u
#define OFF_WP  6094848u
#define OFF_BAR 6160384u   // barrier counters (16B-aligned byte offset 12320768)

__device__ __forceinline__ unsigned short f2b(float f) {
    union { float f; unsigned int u; } c; c.f = f;
    unsigned int u = c.u + 0x7FFFu + ((c.u >> 16) & 1u);
    return (unsigned short)(u >> 16);
}
__device__ __forceinline__ unsigned int pk2(float lo, float hi) {
    union { float f; unsigned int u; } a, b;
    a.f = lo; b.f = hi;
    return __builtin_amdgcn_perm(b.u + 0x8000u, a.u + 0x8000u, 0x07060302u);
}
// single-instruction bf16 pair pack (RNE)
__device__ __forceinline__ unsigned int cvtpk(float lo, float hi) {
    unsigned int r;
    asm("v_cvt_pk_bf16_f32 %0, %1, %2" : "=v"(r) : "v"(lo), "v"(hi));
    return r;
}
// raw 2^x (log2e pre-folded into the Q scale in the qkv phase)
__device__ __forceinline__ float fexp2(float x) {
#if __has_builtin(__builtin_amdgcn_exp2f)
    return __builtin_amdgcn_exp2f(x);
#else
    return exp2f(x);
#endif
}

// Software grid barrier: one-shot counter per phase boundary (zeroed by
// hipMemsetAsync each launch). Release: __threadfence before arrival add.
// Acquire: __threadfence (L1 inv) after spin. Co-residency guaranteed:
// __launch_bounds__(256,3) => 3 blocks/CU capacity = 768 >= 576 blocks.
// Bounded spin guard (~0.2s) converts a placement failure into a wrong
// answer instead of a harness timeout.
__device__ __forceinline__ void gbar(unsigned int* cnt) {
    __syncthreads();
    if (threadIdx.x == 0) {
        __threadfence();
        atomicAdd(cnt, 1u);
        int guard = 0;
        while (__hip_atomic_load(cnt, __ATOMIC_RELAXED, __HIP_MEMORY_SCOPE_AGENT)
                   < (unsigned)NBLK && guard < (1 << 20)) {
            __builtin_amdgcn_s_sleep(8);
            ++guard;
        }
    }
    __syncthreads();
    __threadfence();
}

// ---------------------------------------------------------------------------
// Fused pipeline: prep -> qkv GEMM -> flash attn -> proj GEMM in ONE regular
// launch, software grid barrier between phases. Phase bodies = R4-verified
// kernels verbatim, blockIdx decompositions mapped onto a flat 576 grid.
// Shared memory: 20.5 KB union re-cast per phase.
// ---------------------------------------------------------------------------
__global__ __launch_bounds__(256, 3) void fused_pipeline(
        const float* __restrict__ x, unsigned short* __restrict__ xT,
        const float* __restrict__ wqkv, const float* __restrict__ wproj,
        unsigned short* __restrict__ wq, unsigned short* __restrict__ wp,
        const float* __restrict__ bqkv,
        unsigned short* __restrict__ Qg, unsigned short* __restrict__ Kg,
        unsigned short* __restrict__ Vg, unsigned short* __restrict__ OtT,
        const float* __restrict__ bproj, float* __restrict__ out,
        unsigned int* __restrict__ bar)
{
    __shared__ __align__(16) unsigned char smem[20480];
    const int bid = blockIdx.x;
    const int tid = threadIdx.x;

    // ================= Phase 1: prep (x -> xT bf16 frag-major; weights) ====
    if (bid < 288) {
        unsigned short (*t_s)[72] = reinterpret_cast<unsigned short(*)[72]>(smem);
        const int bx = bid % 36, by = (bid / 36) & 3, b = bid / 144;
        const int n0 = bx * 64, c0 = by * 64;
        const int nl = tid & 63, cq = tid >> 6;
        #pragma unroll
        for (int p = 0; p < 8; ++p) {
            const int c = p * 8 + cq * 2;
            const float f0 = x[((size_t)b * C_DIM + c0 + c) * NPIX + n0 + nl];
            const float f1 = x[((size_t)b * C_DIM + c0 + c + 1) * NPIX + n0 + nl];
            *(unsigned int*)&t_s[nl][c] = pk2(f0, f1);
        }
        __syncthreads();
        const int row = tid >> 2, jq = tid & 3;
        #pragma unroll
        for (int hh = 0; hh < 2; ++hh) {
            const int jl = jq * 2 + hh;
            const int jg = by * 8 + jl;
            const int ngrp = bx * 4 + (row >> 4);
            unsigned short* dst = xT + (((size_t)b * NGRP + ngrp) * 32 + jg) * 128 + (row & 15) * 8;
            *(uint4*)dst = *(uint4*)&t_s[row][jl * 8];
        }
    } else if (bid < 416) {
        const int t = (bid - 288) * 256 + tid;
        const float* src; unsigned short* dst;
        if (t < 24576) {
            const int m = t >> 5, j = t & 31;
            src = wqkv + ((size_t)m * C_DIM + j * 8);
            dst = wq + ((size_t)((m >> 4) * 32 + j) * 16 + (m & 15)) * 8;
        } else {
            const int t2 = t - 24576, m = t2 >> 5, j = t2 & 31;
            src = wproj + ((size_t)m * C_DIM + j * 8);
            dst = wp + ((size_t)((m >> 4) * 32 + j) * 16 + (m & 15)) * 8;
        }
        const float4 f0 = *(const float4*)src, f1 = *(const float4*)(src + 4);
        *(uint4*)dst = make_uint4(pk2(f0.x, f0.y), pk2(f0.z, f0.w),
                                  pk2(f1.x, f1.y), pk2(f1.z, f1.w));
    }
    gbar(bar + 0);

    // ================= Phase 2: qkv GEMM (432 tiles) ========================
    if (bid < 432) {
        const int wv = tid >> 6, lane = tid & 63;
        const int l15 = lane & 15, quad = lane >> 4;
        const int bx = bid % 9, my = (bid / 9) % 24, b = bid / 216;
        const int n0 = bx * 256;
        const int nw = n0 + wv * 64;

        bf16x8 af[2][8];
        #pragma unroll
        for (int mt = 0; mt < 2; ++mt)
            #pragma unroll
            for (int kc = 0; kc < 8; ++kc)
                af[mt][kc] = *(const bf16x8*)(wq +
                    ((size_t)((my * 2 + mt) * 32 + kc * 4 + quad) * 16 + l15) * 8);

        f32x4 acc[2][4];
        #pragma unroll
        for (int mt = 0; mt < 2; ++mt)
            #pragma unroll
            for (int s = 0; s < 4; ++s) acc[mt][s] = (f32x4){0.f, 0.f, 0.f, 0.f};

        #pragma unroll
        for (int sub = 0; sub < 4; ++sub) {
            const int ngrp = (nw + sub * 16) >> 4;
            const unsigned short* bp = xT + ((size_t)b * NGRP + ngrp) * 32 * 128;
            #pragma unroll
            for (int kc = 0; kc < 8; ++kc) {
                const bf16x8 bf = *(const bf16x8*)(bp + (size_t)(kc * 4 + quad) * 128 + l15 * 8);
                acc[0][sub] = __builtin_amdgcn_mfma_f32_16x16x32_bf16(af[0][kc], bf, acc[0][sub], 0, 0, 0);
                acc[1][sub] = __builtin_amdgcn_mfma_f32_16x16x32_bf16(af[1][kc], bf, acc[1][sub], 0, 0, 0);
            }
        }

        const int which = my >> 3;          // block-uniform: 0=q, 1=k, 2=v
        const int h = my & 7, bh = b * NH + h;
        float4 b4[2];
        b4[0] = *(const float4*)(bqkv + my * 32 + quad * 4);
        b4[1] = *(const float4*)(bqkv + my * 32 + 16 + quad * 4);
        unsigned short* wl = (unsigned short*)smem + wv * 2560;

        if (which < 2) {
            // q-scale = (1/sqrt(32)) * log2(e) so softmax can use exp2 directly
            const float sc = (which == 0) ? 0.2550348576f : 1.0f;
            #pragma unroll
            for (int mt = 0; mt < 2; ++mt)
                #pragma unroll
                for (int sub = 0; sub < 4; ++sub) {
                    const float v0 = (acc[mt][sub][0] + b4[mt].x) * sc;
                    const float v1 = (acc[mt][sub][1] + b4[mt].y) * sc;
                    const float v2 = (acc[mt][sub][2] + b4[mt].z) * sc;
                    const float v3 = (acc[mt][sub][3] + b4[mt].w) * sc;
                    *(uint2*)&wl[(sub * 16 + l15) * 40 + mt * 16 + quad * 4] =
                        make_uint2(pk2(v0, v1), pk2(v2, v3));
                }
            unsigned short* dst = ((which == 0) ? Qg : Kg)
                                + ((size_t)bh * NPIX + nw + lane) * HD;
            #pragma unroll
            for (int i = 0; i < 4; ++i)
                *((uint4*)dst + i) = *(uint4*)&wl[lane * 40 + i * 8];
        } else {
            #pragma unroll
            for (int mt = 0; mt < 2; ++mt)
                #pragma unroll
                for (int sub = 0; sub < 4; ++sub) {
                    wl[(mt * 16 + quad * 4 + 0) * 72 + sub * 16 + l15] = f2b(acc[mt][sub][0] + b4[mt].x);
                    wl[(mt * 16 + quad * 4 + 1) * 72 + sub * 16 + l15] = f2b(acc[mt][sub][1] + b4[mt].y);
                    wl[(mt * 16 + quad * 4 + 2) * 72 + sub * 16 + l15] = f2b(acc[mt][sub][2] + b4[mt].z);
                    wl[(mt * 16 + quad * 4 + 3) * 72 + sub * 16 + l15] = f2b(acc[mt][sub][3] + b4[mt].w);
                }
            const int row = lane >> 1, seg = (lane & 1) * 32;
            unsigned short* dst = Vg + ((size_t)bh * HD + row) * NPIX + nw + seg;
            #pragma unroll
            for (int i = 0; i < 4; ++i)
                *((uint4*)dst + i) = *(uint4*)&wl[row * 72 + seg + i * 8];
        }
    }
    gbar(bar + 1);

    // ================= Phase 3: flash attention (576 tiles) =================
    {
        // shared layout: k [2][64][40] shorts @0, v [2][32][76] shorts @5120
        unsigned short* ksb = (unsigned short*)smem;           // 5120 shorts
        unsigned short* vsb = (unsigned short*)smem + 5120;    // 4864 shorts

        const int wv = tid >> 6, lane = tid & 63;
        const int l15 = lane & 15, quad = lane >> 4;
        const int bh = bid & 15;
        const int q0 = (bid >> 4) * 64;

        const unsigned short* Qh = Qg + (size_t)bh * NPIX * HD;
        const unsigned short* Kh = Kg + (size_t)bh * NPIX * HD;
        const unsigned short* Vh = Vg + (size_t)bh * HD * NPIX;

        const bf16x8 q_frag = *(const bf16x8*)(Qh + (size_t)(q0 + wv * 16 + l15) * HD + quad * 8);
        const bf16x8 onesf = {16256, 16256, 16256, 16256, 16256, 16256, 16256, 16256}; // bf16 1.0

        const int kr = tid >> 2, kc = (tid & 3) * 8;
        // sigma(k): slot = 32*k5 + 16*k2 + 8*k4 + 4*k3 + 2*k1 + k0
        const int ksl = (kr & 0x23) | ((kr & 0x04) << 2) | ((kr & 0x18) >> 1);
        const int vd = tid >> 3, vc = (tid & 7) * 8;

        uint4 kreg = *(const uint4*)(Kh + (size_t)kr * HD + kc);
        uint4 vreg = *(const uint4*)(Vh + (size_t)vd * NPIX + vc);
        *(uint4*)(ksb + ksl * 40 + kc) = kreg;
        *(uint4*)(vsb + vd * 76 + vc) = vreg;

        f32x4 o0 = {0.f, 0.f, 0.f, 0.f};
        f32x4 o1 = {0.f, 0.f, 0.f, 0.f};
        f32x4 ol = {0.f, 0.f, 0.f, 0.f};       // row-sum accumulator (ones-row MFMA)

        for (int t = 0; t < TPB; ++t) {
            const int cur = t & 1;
            if (t + 1 < TPB) {
                const int k0 = (t + 1) * TK;
                kreg = *(const uint4*)(Kh + (size_t)(k0 + kr) * HD + kc);
                vreg = *(const uint4*)(Vh + (size_t)vd * NPIX + k0 + vc);
            }
            __syncthreads();

            f32x4 s[4];
            #pragma unroll
            for (int kg = 0; kg < 4; ++kg) {
                const bf16x8 kf = *(const bf16x8*)(ksb + cur * 2560 + (kg * 16 + l15) * 40 + quad * 8);
                s[kg] = __builtin_amdgcn_mfma_f32_16x16x32_bf16(kf, q_frag,
                            (f32x4){0.f, 0.f, 0.f, 0.f}, 0, 0, 0);
            }

            // exp2 + pack: registers ARE the PV B-fragment under the sigma layout
            bf16x8 pf[2];
            #pragma unroll
            for (int kc2 = 0; kc2 < 2; ++kc2) {
                union { unsigned int u[4]; bf16x8 v; } c;
                c.u[0] = cvtpk(fexp2(s[2 * kc2][0]),     fexp2(s[2 * kc2][1]));
                c.u[1] = cvtpk(fexp2(s[2 * kc2][2]),     fexp2(s[2 * kc2][3]));
                c.u[2] = cvtpk(fexp2(s[2 * kc2 + 1][0]), fexp2(s[2 * kc2 + 1][1]));
                c.u[3] = cvtpk(fexp2(s[2 * kc2 + 1][2]), fexp2(s[2 * kc2 + 1][3]));
                pf[kc2] = c.v;
            }

            #pragma unroll
            for (int kc2 = 0; kc2 < 2; ++kc2) {
                const bf16x8 vf0 = *(const bf16x8*)(vsb + cur * 2432 + l15 * 76 + kc2 * 32 + quad * 8);
                const bf16x8 vf1 = *(const bf16x8*)(vsb + cur * 2432 + (16 + l15) * 76 + kc2 * 32 + quad * 8);
                o0 = __builtin_amdgcn_mfma_f32_16x16x32_bf16(vf0, pf[kc2], o0, 0, 0, 0);
                o1 = __builtin_amdgcn_mfma_f32_16x16x32_bf16(vf1, pf[kc2], o1, 0, 0, 0);
                ol = __builtin_amdgcn_mfma_f32_16x16x32_bf16(onesf, pf[kc2], ol, 0, 0, 0);
            }

            if (t + 1 < TPB) {
                *(uint4*)(ksb + (cur ^ 1) * 2560 + ksl * 40 + kc) = kreg;
                *(uint4*)(vsb + (cur ^ 1) * 2432 + vd * 76 + vc) = vreg;
            }
        }

        // Epilogue: normalize in-register, write fragment-major bf16 OtT.
        const float inv = 1.f / ol[0];
        const int b = bh >> 3, h = bh & 7;
        const int qg = q0 + wv * 16 + l15;
        unsigned short* base = OtT + (((size_t)b * NGRP + (qg >> 4)) * 32 + h * 4) * 128
                             + (qg & 15) * 8;
        const int jq0 = quad >> 1, half = (quad & 1) * 4;
        const uint2 w0 = make_uint2(cvtpk(o0[0] * inv, o0[1] * inv),
                                    cvtpk(o0[2] * inv, o0[3] * inv));
        const uint2 w1 = make_uint2(cvtpk(o1[0] * inv, o1[1] * inv),
                                    cvtpk(o1[2] * inv, o1[3] * inv));
        *(uint2*)(base + (size_t)jq0 * 128 + half)       = w0;
        *(uint2*)(base + (size_t)(2 + jq0) * 128 + half) = w1;
    }
    gbar(bar + 2);

    // ================= Phase 4: proj GEMM + bias + residual (576 tiles) =====
    {
        const int wv = tid >> 6, lane = tid & 63;
        const int l15 = lane & 15, quad = lane >> 4;
        const int bx = bid % 18, my = (bid / 18) & 15, b = bid / 288;
        const int n0 = bx * 128;
        const int nw = n0 + wv * 32;

        bf16x8 af[8];
        #pragma unroll
        for (int kc = 0; kc < 8; ++kc)
            af[kc] = *(const bf16x8*)(wp + ((size_t)(my * 32 + kc * 4 + quad) * 16 + l15) * 8);

        f32x4 acc[2];
        acc[0] = (f32x4){0.f, 0.f, 0.f, 0.f};
        acc[1] = (f32x4){0.f, 0.f, 0.f, 0.f};

        #pragma unroll
        for (int sub = 0; sub < 2; ++sub) {
            const int ngrp = (nw + sub * 16) >> 4;
            const unsigned short* bp = OtT + ((size_t)b * NGRP + ngrp) * 32 * 128;
            #pragma unroll
            for (int kc = 0; kc < 8; ++kc) {
                const bf16x8 bf = *(const bf16x8*)(bp + (size_t)(kc * 4 + quad) * 128 + l15 * 8);
                acc[sub] = __builtin_amdgcn_mfma_f32_16x16x32_bf16(af[kc], bf, acc[sub], 0, 0, 0);
            }
        }

        float* wl = (float*)smem + wv * 576;
        #pragma unroll
        for (int sub = 0; sub < 2; ++sub) {
            wl[(quad * 4 + 0) * 36 + sub * 16 + l15] = acc[sub][0];
            wl[(quad * 4 + 1) * 36 + sub * 16 + l15] = acc[sub][1];
            wl[(quad * 4 + 2) * 36 + sub * 16 + l15] = acc[sub][2];
            wl[(quad * 4 + 3) * 36 + sub * 16 + l15] = acc[sub][3];
        }
        const int m0 = my * 16;
        #pragma unroll
        for (int p = 0; p < 2; ++p) {
            const int row = p * 8 + (lane >> 3), cn = (lane & 7) * 4;
            const int c = m0 + row;
            const size_t idx = ((size_t)b * C_DIM + c) * NPIX + nw + cn;
            const f32x4 v = *(const f32x4*)&wl[row * 36 + cn];
            const f32x4 r = *(const f32x4*)(x + idx);
            const float bv = bproj[c];
            f32x4 o;
            o[0] = v[0] + bv + r[0]; o[1] = v[1] + bv + r[1];
            o[2] = v[2] + bv + r[2]; o[3] = v[3] + bv + r[3];
            *(f32x4*)(out + idx) = o;
        }
    }
}

// ---------------------------------------------------------------------------
extern "C" void kernel_launch(void* const* d_in, const int* in_sizes, int n_in,
                              void* d_out, int out_size, void* d_ws, size_t ws_size,
                              hipStream_t stream)
{
    const float* x      = (const float*)d_in[0];
    const float* w_qkv  = (const float*)d_in[1];
    const float* b_qkv  = (const float*)d_in[2];
    const float* w_proj = (const float*)d_in[3];
    const float* b_proj = (const float*)d_in[4];
    float* out = (float*)d_out;

    unsigned short* ws = (unsigned short*)d_ws;
    unsigned short* xT  = ws + OFF_XT;
    unsigned short* Qg  = ws + OFF_Q;
    unsigned short* Kg  = ws + OFF_K;
    unsigned short* Vg  = ws + OFF_V;
    unsigned short* OtT = ws + OFF_OT;
    unsigned short* wq  = ws + OFF_WQ;
    unsigned short* wp  = ws + OFF_WP;
    unsigned int* bar   = (unsigned int*)(ws + OFF_BAR);

    // zero the 3 one-shot barrier counters (async, graph-capture safe)
    hipMemsetAsync(bar, 0, 64, stream);
    fused_pipeline<<<dim3(NBLK), 256, 0, stream>>>(
        x, xT, w_qkv, w_proj, wq, wp, b_qkv,
        Qg, Kg, Vg, OtT, b_proj, out, bar);
}

// Round 7
// 105.809 us; speedup vs baseline: 3.7752x; 3.7752x over previous
//
#include <hip/hip_runtime.h>
#include <math.h>

#define C_DIM 256
#define NH 8
#define HD 32
#define BATCH 2
#define NPIX 2304        // 48*48
#define TK 64
#define NGRP (NPIX / 16) // 144 n-groups of 16
#define TPB 36           // K-tiles per attn block (full range, no split-K)

typedef __attribute__((ext_vector_type(8))) short bf16x8;
typedef __attribute__((ext_vector_type(4))) float f32x4;

// workspace offsets (in shorts)
#define OFF_XT  0u
#define OFF_Q   1179648u
#define OFF_K   2359296u
#define OFF_V   3538944u
#define OFF_OT  4718592u
#define OFF_WQ  5898240u
#define OFF_WP  6094848u

__device__ __forceinline__ unsigned short f2b(float f) {
    union { float f; unsigned int u; } c; c.f = f;
    unsigned int u = c.u + 0x7FFFu + ((c.u >> 16) & 1u);
    return (unsigned short)(u >> 16);
}
__device__ __forceinline__ unsigned int pk2(float lo, float hi) {
    union { float f; unsigned int u; } a, b;
    a.f = lo; b.f = hi;
    return __builtin_amdgcn_perm(b.u + 0x8000u, a.u + 0x8000u, 0x07060302u);
}
// single-instruction bf16 pair pack (RNE) — T12 recipe
__device__ __forceinline__ unsigned int cvtpk(float lo, float hi) {
    unsigned int r;
    asm("v_cvt_pk_bf16_f32 %0, %1, %2" : "=v"(r) : "v"(lo), "v"(hi));
    return r;
}
// raw 2^x (log2e is pre-folded into the Q scale in qkv_gemm)
__device__ __forceinline__ float fexp2(float x) {
#if __has_builtin(__builtin_amdgcn_exp2f)
    return __builtin_amdgcn_exp2f(x);
#else
    return exp2f(x);
#endif
}

// ---------------------------------------------------------------------------
// Prep (merged): blocks 0..575 = x f32 -> xT bf16 fragment-major (32c x 64n
// tiles: 2x the blocks of the old 64c version -> 2.25 blocks/CU instead of
// 1.1, halved per-block serial work), blocks 576..703 = weights.
// grid 704 x 256.
// ---------------------------------------------------------------------------
__global__ __launch_bounds__(256) void prep_all(
        const float* __restrict__ x, unsigned short* __restrict__ xT,
        const float* __restrict__ wqkv, const float* __restrict__ wproj,
        unsigned short* __restrict__ wq, unsigned short* __restrict__ wp)
{
    __shared__ unsigned short t_s[64][40];
    const int bid = blockIdx.x;
    const int tid = threadIdx.x;
    if (bid < 576) {
        const int bx = bid % 36, by = (bid / 36) & 7, b = bid / 288;
        const int n0 = bx * 64, c0 = by * 32;
        const int nl = tid & 63, cq = tid >> 6;      // cq 0..3
        #pragma unroll
        for (int p = 0; p < 4; ++p) {
            const int c = p * 8 + cq * 2;            // even, covers 0..30
            const float f0 = x[((size_t)b * C_DIM + c0 + c) * NPIX + n0 + nl];
            const float f1 = x[((size_t)b * C_DIM + c0 + c + 1) * NPIX + n0 + nl];
            *(unsigned int*)&t_s[nl][c] = pk2(f0, f1);
        }
        __syncthreads();
        const int row = tid >> 2, jl = tid & 3;
        const int jg = by * 4 + jl;                  // c-octet 0..31
        const int ngrp = bx * 4 + (row >> 4);
        unsigned short* dst = xT + (((size_t)b * NGRP + ngrp) * 32 + jg) * 128 + (row & 15) * 8;
        *(uint4*)dst = *(uint4*)&t_s[row][jl * 8];
    } else {
        const int t = (bid - 576) * 256 + tid;
        const float* src; unsigned short* dst;
        if (t < 24576) {
            const int m = t >> 5, j = t & 31;
            src = wqkv + ((size_t)m * C_DIM + j * 8);
            dst = wq + ((size_t)((m >> 4) * 32 + j) * 16 + (m & 15)) * 8;
        } else {
            const int t2 = t - 24576, m = t2 >> 5, j = t2 & 31;
            src = wproj + ((size_t)m * C_DIM + j * 8);
            dst = wp + ((size_t)((m >> 4) * 32 + j) * 16 + (m & 15)) * 8;
        }
        const float4 f0 = *(const float4*)src, f1 = *(const float4*)(src + 4);
        *(uint4*)dst = make_uint4(pk2(f0.x, f0.y), pk2(f0.z, f0.w),
                                  pk2(f1.x, f1.y), pk2(f1.z, f1.w));
    }
}

// ---------------------------------------------------------------------------
// Kernel 1: qkv GEMM, streaming, m=32 per block. grid (9, 24, 2).
// Q scale folds log2(e) so attn can use raw v_exp_f32 (2^x).
// ---------------------------------------------------------------------------
__global__ __launch_bounds__(256, 2) void qkv_gemm(
        const unsigned short* __restrict__ xT, const unsigned short* __restrict__ wq,
        const float* __restrict__ bias,
        unsigned short* __restrict__ Qg, unsigned short* __restrict__ Kg,
        unsigned short* __restrict__ Vg)
{
    __shared__ unsigned short eplds[4][2560];
    const int tid = threadIdx.x, wv = tid >> 6, lane = tid & 63;
    const int l15 = lane & 15, quad = lane >> 4;
    const int n0 = blockIdx.x * 256, my = blockIdx.y, b = blockIdx.z;
    const int nw = n0 + wv * 64;

    bf16x8 af[2][8];
    #pragma unroll
    for (int mt = 0; mt < 2; ++mt)
        #pragma unroll
        for (int kc = 0; kc < 8; ++kc)
            af[mt][kc] = *(const bf16x8*)(wq +
                ((size_t)((my * 2 + mt) * 32 + kc * 4 + quad) * 16 + l15) * 8);

    f32x4 acc[2][4];
    #pragma unroll
    for (int mt = 0; mt < 2; ++mt)
        #pragma unroll
        for (int s = 0; s < 4; ++s) acc[mt][s] = (f32x4){0.f, 0.f, 0.f, 0.f};

    #pragma unroll
    for (int sub = 0; sub < 4; ++sub) {
        const int ngrp = (nw + sub * 16) >> 4;
        const unsigned short* bp = xT + ((size_t)b * NGRP + ngrp) * 32 * 128;
        #pragma unroll
        for (int kc = 0; kc < 8; ++kc) {
            const bf16x8 bf = *(const bf16x8*)(bp + (size_t)(kc * 4 + quad) * 128 + l15 * 8);
            acc[0][sub] = __builtin_amdgcn_mfma_f32_16x16x32_bf16(af[0][kc], bf, acc[0][sub], 0, 0, 0);
            acc[1][sub] = __builtin_amdgcn_mfma_f32_16x16x32_bf16(af[1][kc], bf, acc[1][sub], 0, 0, 0);
        }
    }

    const int which = my >> 3;          // block-uniform: 0=q, 1=k, 2=v
    const int h = my & 7, bh = b * NH + h;
    float4 b4[2];
    b4[0] = *(const float4*)(bias + my * 32 + quad * 4);
    b4[1] = *(const float4*)(bias + my * 32 + 16 + quad * 4);
    unsigned short* wl = eplds[wv];

    if (which < 2) {
        // q-scale = (1/sqrt(32)) * log2(e) so softmax can use exp2 directly
        const float sc = (which == 0) ? 0.2550348576f : 1.0f;
        #pragma unroll
        for (int mt = 0; mt < 2; ++mt)
            #pragma unroll
            for (int sub = 0; sub < 4; ++sub) {
                const float v0 = (acc[mt][sub][0] + b4[mt].x) * sc;
                const float v1 = (acc[mt][sub][1] + b4[mt].y) * sc;
                const float v2 = (acc[mt][sub][2] + b4[mt].z) * sc;
                const float v3 = (acc[mt][sub][3] + b4[mt].w) * sc;
                *(uint2*)&wl[(sub * 16 + l15) * 40 + mt * 16 + quad * 4] =
                    make_uint2(pk2(v0, v1), pk2(v2, v3));
            }
        unsigned short* dst = ((which == 0) ? Qg : Kg)
                            + ((size_t)bh * NPIX + nw + lane) * HD;
        #pragma unroll
        for (int i = 0; i < 4; ++i)
            *((uint4*)dst + i) = *(uint4*)&wl[lane * 40 + i * 8];
    } else {
        #pragma unroll
        for (int mt = 0; mt < 2; ++mt)
            #pragma unroll
            for (int sub = 0; sub < 4; ++sub) {
                wl[(mt * 16 + quad * 4 + 0) * 72 + sub * 16 + l15] = f2b(acc[mt][sub][0] + b4[mt].x);
                wl[(mt * 16 + quad * 4 + 1) * 72 + sub * 16 + l15] = f2b(acc[mt][sub][1] + b4[mt].y);
                wl[(mt * 16 + quad * 4 + 2) * 72 + sub * 16 + l15] = f2b(acc[mt][sub][2] + b4[mt].z);
                wl[(mt * 16 + quad * 4 + 3) * 72 + sub * 16 + l15] = f2b(acc[mt][sub][3] + b4[mt].w);
            }
        const int row = lane >> 1, seg = (lane & 1) * 32;
        unsigned short* dst = Vg + ((size_t)bh * HD + row) * NPIX + nw + seg;
        #pragma unroll
        for (int i = 0; i < 4; ++i)
            *((uint4*)dst + i) = *(uint4*)&wl[row * 72 + seg + i * 8];
    }
}

// ---------------------------------------------------------------------------
// Kernel 2: MFMA flash attention, NO split-K (block owns full denominator).
// Each wave: 16 q rows, 36 K-tiles of 64. K staged under sigma bit-shuffle
// (slot={k5,k2,k4,k3,k1,k0}) so QK^T output registers after exp2+cvt_pk ARE
// the PV B-fragment (no P LDS round-trip). Epilogue: inv = 1/lsum in-lane
// (ones-row MFMA puts lsum[q=l15] in ol[0] on every lane), normalize in
// registers, write fragment-major bf16 OtT directly.
// grid (16, 36).
// ---------------------------------------------------------------------------
__global__ __launch_bounds__(256, 4) void attn_kernel(
        const unsigned short* __restrict__ Qg, const unsigned short* __restrict__ Kg,
        const unsigned short* __restrict__ Vg,
        unsigned short* __restrict__ OtT)
{
    __shared__ unsigned short k_s[2][TK][40];
    __shared__ unsigned short v_s[2][HD][76];

    const int tid  = threadIdx.x;
    const int wv   = tid >> 6;
    const int lane = tid & 63;
    const int l15  = lane & 15;
    const int quad = lane >> 4;
    const int bh   = blockIdx.x;
    const int q0   = blockIdx.y * 64;

    const unsigned short* Qh = Qg + (size_t)bh * NPIX * HD;
    const unsigned short* Kh = Kg + (size_t)bh * NPIX * HD;
    const unsigned short* Vh = Vg + (size_t)bh * HD * NPIX;

    const bf16x8 q_frag = *(const bf16x8*)(Qh + (size_t)(q0 + wv * 16 + l15) * HD + quad * 8);
    const bf16x8 onesf = {16256, 16256, 16256, 16256, 16256, 16256, 16256, 16256}; // bf16 1.0

    const int kr = tid >> 2, kc = (tid & 3) * 8;
    // sigma(k): slot = 32*k5 + 16*k2 + 8*k4 + 4*k3 + 2*k1 + k0 (loop-invariant)
    const int ksl = (kr & 0x23) | ((kr & 0x04) << 2) | ((kr & 0x18) >> 1);
    const int vd = tid >> 3, vc = (tid & 7) * 8;

    uint4 kreg = *(const uint4*)(Kh + (size_t)kr * HD + kc);
    uint4 vreg = *(const uint4*)(Vh + (size_t)vd * NPIX + vc);
    *(uint4*)&k_s[0][ksl][kc] = kreg;
    *(uint4*)&v_s[0][vd][vc] = vreg;

    f32x4 o0 = {0.f, 0.f, 0.f, 0.f};
    f32x4 o1 = {0.f, 0.f, 0.f, 0.f};
    f32x4 ol = {0.f, 0.f, 0.f, 0.f};           // row-sum accumulator (ones-row MFMA)

    for (int t = 0; t < TPB; ++t) {
        const int cur = t & 1;
        if (t + 1 < TPB) {
            const int k0 = (t + 1) * TK;
            kreg = *(const uint4*)(Kh + (size_t)(k0 + kr) * HD + kc);
            vreg = *(const uint4*)(Vh + (size_t)vd * NPIX + k0 + vc);
        }
        __syncthreads();

        f32x4 s[4];
        #pragma unroll
        for (int kg = 0; kg < 4; ++kg) {
            const bf16x8 kf = *(const bf16x8*)&k_s[cur][kg * 16 + l15][quad * 8];
            s[kg] = __builtin_amdgcn_mfma_f32_16x16x32_bf16(kf, q_frag,
                        (f32x4){0.f, 0.f, 0.f, 0.f}, 0, 0, 0);
        }

        // exp2 + pack: registers ARE the PV B-fragment under the sigma layout
        bf16x8 pf[2];
        #pragma unroll
        for (int kc2 = 0; kc2 < 2; ++kc2) {
            union { unsigned int u[4]; bf16x8 v; } c;
            c.u[0] = cvtpk(fexp2(s[2 * kc2][0]),     fexp2(s[2 * kc2][1]));
            c.u[1] = cvtpk(fexp2(s[2 * kc2][2]),     fexp2(s[2 * kc2][3]));
            c.u[2] = cvtpk(fexp2(s[2 * kc2 + 1][0]), fexp2(s[2 * kc2 + 1][1]));
            c.u[3] = cvtpk(fexp2(s[2 * kc2 + 1][2]), fexp2(s[2 * kc2 + 1][3]));
            pf[kc2] = c.v;
        }

        #pragma unroll
        for (int kc2 = 0; kc2 < 2; ++kc2) {
            const bf16x8 vf0 = *(const bf16x8*)&v_s[cur][l15][kc2 * 32 + quad * 8];
            const bf16x8 vf1 = *(const bf16x8*)&v_s[cur][16 + l15][kc2 * 32 + quad * 8];
            o0 = __builtin_amdgcn_mfma_f32_16x16x32_bf16(vf0, pf[kc2], o0, 0, 0, 0);
            o1 = __builtin_amdgcn_mfma_f32_16x16x32_bf16(vf1, pf[kc2], o1, 0, 0, 0);
            ol = __builtin_amdgcn_mfma_f32_16x16x32_bf16(onesf, pf[kc2], ol, 0, 0, 0);
        }

        if (t + 1 < TPB) {
            *(uint4*)&k_s[cur ^ 1][ksl][kc] = kreg;
            *(uint4*)&v_s[cur ^ 1][vd][vc] = vreg;
        }
    }

    // Epilogue: o0[r] = O[d=quad*4+r][q=l15], o1[r] = O[d=16+quad*4+r][q=l15].
    // ol rows identical (A = ones) => ol[0] = lsum for q=l15 on this very lane.
    const float inv = 1.f / ol[0];
    const int b = bh >> 3, h = bh & 7;
    const int qg = q0 + wv * 16 + l15;
    // OtT fragment cell: [b][ngrp=qg>>4][j=h*4+jq][qlocal=qg&15][8 shorts]
    unsigned short* base = OtT + (((size_t)b * NGRP + (qg >> 4)) * 32 + h * 4) * 128
                         + (qg & 15) * 8;
    const int jq0 = quad >> 1, half = (quad & 1) * 4;
    const uint2 w0 = make_uint2(cvtpk(o0[0] * inv, o0[1] * inv),
                                cvtpk(o0[2] * inv, o0[3] * inv));
    const uint2 w1 = make_uint2(cvtpk(o1[0] * inv, o1[1] * inv),
                                cvtpk(o1[2] * inv, o1[3] * inv));
    *(uint2*)(base + (size_t)jq0 * 128 + half)       = w0;   // d = quad*4 + 0..3
    *(uint2*)(base + (size_t)(2 + jq0) * 128 + half) = w1;   // d = 16 + quad*4 + 0..3
}

// ---------------------------------------------------------------------------
// Kernel 3: proj GEMM, streaming + fused bias/residual (unchanged).
// grid (18, 16, 2).
// ---------------------------------------------------------------------------
__global__ __launch_bounds__(256) void proj_gemm(
        const unsigned short* __restrict__ OtT, const unsigned short* __restrict__ wp,
        const float* __restrict__ bias, const float* __restrict__ x,
        float* __restrict__ out)
{
    __shared__ float plds[4][576];
    const int tid = threadIdx.x, wv = tid >> 6, lane = tid & 63;
    const int l15 = lane & 15, quad = lane >> 4;
    const int n0 = blockIdx.x * 128, my = blockIdx.y, b = blockIdx.z;
    const int nw = n0 + wv * 32;

    bf16x8 af[8];
    #pragma unroll
    for (int kc = 0; kc < 8; ++kc)
        af[kc] = *(const bf16x8*)(wp + ((size_t)(my * 32 + kc * 4 + quad) * 16 + l15) * 8);

    f32x4 acc[2];
    acc[0] = (f32x4){0.f, 0.f, 0.f, 0.f};
    acc[1] = (f32x4){0.f, 0.f, 0.f, 0.f};

    #pragma unroll
    for (int sub = 0; sub < 2; ++sub) {
        const int ngrp = (nw + sub * 16) >> 4;
        const unsigned short* bp = OtT + ((size_t)b * NGRP + ngrp) * 32 * 128;
        #pragma unroll
        for (int kc = 0; kc < 8; ++kc) {
            const bf16x8 bf = *(const bf16x8*)(bp + (size_t)(kc * 4 + quad) * 128 + l15 * 8);
            acc[sub] = __builtin_amdgcn_mfma_f32_16x16x32_bf16(af[kc], bf, acc[sub], 0, 0, 0);
        }
    }

    float* wl = plds[wv];
    #pragma unroll
    for (int sub = 0; sub < 2; ++sub) {
        wl[(quad * 4 + 0) * 36 + sub * 16 + l15] = acc[sub][0];
        wl[(quad * 4 + 1) * 36 + sub * 16 + l15] = acc[sub][1];
        wl[(quad * 4 + 2) * 36 + sub * 16 + l15] = acc[sub][2];
        wl[(quad * 4 + 3) * 36 + sub * 16 + l15] = acc[sub][3];
    }
    const int m0 = my * 16;
    #pragma unroll
    for (int p = 0; p < 2; ++p) {
        const int row = p * 8 + (lane >> 3), cn = (lane & 7) * 4;
        const int c = m0 + row;
        const size_t idx = ((size_t)b * C_DIM + c) * NPIX + nw + cn;
        const f32x4 v = *(const f32x4*)&wl[row * 36 + cn];
        const f32x4 r = *(const f32x4*)(x + idx);
        const float bv = bias[c];
        f32x4 o;
        o[0] = v[0] + bv + r[0]; o[1] = v[1] + bv + r[1];
        o[2] = v[2] + bv + r[2]; o[3] = v[3] + bv + r[3];
        *(f32x4*)(out + idx) = o;
    }
}

// ---------------------------------------------------------------------------
extern "C" void kernel_launch(void* const* d_in, const int* in_sizes, int n_in,
                              void* d_out, int out_size, void* d_ws, size_t ws_size,
                              hipStream_t stream)
{
    const float* x      = (const float*)d_in[0];
    const float* w_qkv  = (const float*)d_in[1];
    const float* b_qkv  = (const float*)d_in[2];
    const float* w_proj = (const float*)d_in[3];
    const float* b_proj = (const float*)d_in[4];
    float* out = (float*)d_out;

    unsigned short* ws = (unsigned short*)d_ws;
    unsigned short* xT  = ws + OFF_XT;
    unsigned short* Qg  = ws + OFF_Q;
    unsigned short* Kg  = ws + OFF_K;
    unsigned short* Vg  = ws + OFF_V;
    unsigned short* OtT = ws + OFF_OT;
    unsigned short* wq  = ws + OFF_WQ;
    unsigned short* wp  = ws + OFF_WP;

    prep_all<<<dim3(704), 256, 0, stream>>>(x, xT, w_qkv, w_proj, wq, wp);
    qkv_gemm<<<dim3(9, 24, 2), 256, 0, stream>>>(xT, wq, b_qkv, Qg, Kg, Vg);
    attn_kernel<<<dim3(16, 36), 256, 0, stream>>>(Qg, Kg, Vg, OtT);
    proj_gemm<<<dim3(18, 16, 2), 256, 0, stream>>>(OtT, wp, b_proj, x, out);
}